// Round 5
// baseline (66383.911 us; speedup 1.0000x reference)
//
#include <hip/hip_runtime.h>
#include <math.h>
#include <utility>

#define TB 1024   // batch
#define HH 100    // hidden

// ---------------------------------------------------------------------------
// NUMERICS ARE FROZEN — DO NOT TOUCH.
// Only the ocml expf/tanhf profile lands on the reference side of a
// knife-edge decoder argmax logit near-tie. The transcendentals AND the
// per-element GEMV/gate expression DAG (values, pairing, order) must stay
// bit-identical. Reg-sourced and LDS-sourced 4-term FMA groups are proven
// bit-equivalent (R10 gemv_lds / R11 gemv4 both passed). Chains ascend k.
//
// R15 model (fits R0-R14 within 10%):
//   step cyc/CU = LV_b128*12 + uniform_b128*5 (+ barrier ~300); VALU under.
//   uniform reads/elem = 50 * (waves per team)  <- THE invariant to break.
// R14 facts: pins neutral (R14 big == R10 big); AGPR-resident weight arrays
// are free (direct VALU reads, no scratch: FETCH flat 105MB all rounds).
// R15: 3 gate-rows (r,z,n of output i) per thread -> team = 2 waves:
//   uniform/elem 250->100; r/z stay in regs (no gate LDS round-trip, no B1);
//   h/x double-buffered -> ONE barrier/step. Weights: wih + whh k<40 in regs
//   (~240 floats, AGPR), whh/wih k>=40 in LDS (lane-varying, 3-row reads).
// Block 256 thr = 2 teams x BT=2 = 4 elems, grid 256, 4 waves/CU.
// Projected: enc1 ~6500 cyc/step (was 8800), enc0 ~3900 (was ~8600).
// ---------------------------------------------------------------------------
__device__ __forceinline__ float sigmoidf_(float x) {
    return 1.0f / (1.0f + expf(-x));
}
__device__ __forceinline__ float tanhf_(float x) {
    return tanhf(x);
}

// ---- one k-group (4 values), weights from per-thread registers ----
// acc[g3][b] += w[g3][4G..4G+3] . vec[e0+b][4G..4G+3]   (frozen 4-term shape)
template<int GG, int BT, int LD, int NREG>
__device__ __forceinline__ void grp_reg(const float (&w)[3][NREG],
                                        const float (*vec)[LD], int e0,
                                        float (&acc)[3][BT]) {
    float4 vv[BT];
    #pragma unroll
    for (int b = 0; b < BT; ++b)
        vv[b] = *reinterpret_cast<const float4*>(&vec[e0 + b][GG * 4]);
    #pragma unroll
    for (int g3 = 0; g3 < 3; ++g3) {
        #pragma unroll
        for (int b = 0; b < BT; ++b)
            acc[g3][b] += w[g3][GG * 4]     * vv[b].x + w[g3][GG * 4 + 1] * vv[b].y
                        + w[g3][GG * 4 + 2] * vv[b].z + w[g3][GG * 4 + 3] * vv[b].w;
    }
}
template<int BT, int LD, int NREG, size_t... Is>
__device__ __forceinline__ void dot_reg(std::index_sequence<Is...>,
                                        const float (&w)[3][NREG],
                                        const float (*vec)[LD], int e0,
                                        float (&acc)[3][BT]) {
    (grp_reg<(int)Is, BT, LD, NREG>(w, vec, e0, acc), ...);
}

// ---- one k-group, weights from LDS [3][NG][HH][4] (k-packed per gate) ----
// Same 4-term expression shape; weight k-range = OFF*4 + (GG-OFF)*4 == GG*4.
template<int GG, int OFF, int BT, int LD, int NG>
__device__ __forceinline__ void grp_lds(const float (&wl)[3][NG][HH][4],
                                        int ii,
                                        const float (*vec)[LD], int e0,
                                        float (&acc)[3][BT]) {
    float4 vv[BT];
    #pragma unroll
    for (int b = 0; b < BT; ++b)
        vv[b] = *reinterpret_cast<const float4*>(&vec[e0 + b][GG * 4]);
    #pragma unroll
    for (int g3 = 0; g3 < 3; ++g3) {
        const float4 wv = *reinterpret_cast<const float4*>(wl[g3][GG - OFF][ii]);
        #pragma unroll
        for (int b = 0; b < BT; ++b)
            acc[g3][b] += wv.x * vv[b].x + wv.y * vv[b].y
                        + wv.z * vv[b].z + wv.w * vv[b].w;
    }
}
template<int OFF, int BT, int LD, int NG, size_t... Is>
__device__ __forceinline__ void dot_lds(std::index_sequence<Is...>,
                                        const float (&wl)[3][NG][HH][4],
                                        int ii,
                                        const float (*vec)[LD], int e0,
                                        float (&acc)[3][BT]) {
    (grp_lds<(int)Is + OFF, OFF, BT, LD, NG>(wl, ii, vec, e0, acc), ...);
}

// ===========================================================================
// GRU layer, 3-gates-per-thread. Block 256 = 2 teams x 2 waves (100 active
// threads/team = output i; thread owns rows i, 100+i, 200+i). BT=2 elems per
// team -> 4 elems/block, grid 256. One barrier per step (h/x double-buffer).
// ===========================================================================
template<int K, bool EMB, bool WRITE_SEQ>
__global__ __launch_bounds__(256)
void gru3(const float* __restrict__ xin,   // [T,B,K] (if !EMB)
          const int*   __restrict__ tgt,   // [T,B]   (if EMB)
          const float* __restrict__ emb,   // [64,26] (if EMB)
          const float* __restrict__ Wih,   // [300,K]
          const float* __restrict__ Whh,   // [300,100]
          const float* __restrict__ bih,
          const float* __restrict__ bhh,
          const float* __restrict__ h_init,// [B,100] or null -> zeros
          float* __restrict__ seq_out,     // [T,B,100] (if WRITE_SEQ)
          float* __restrict__ h_last,      // [B,100] or null
          int T)
{
    constexpr int KP   = (K + 3) & ~3;          // 28 or 100
    constexpr int GX   = KP / 4;                // x k-groups: 7 or 25
    constexpr int XREG = (K == 26) ? KP : 40;   // wih k-vals in regs
    constexpr int GXR  = XREG / 4;              // 7 or 10
    constexpr int GXL  = GX - GXR;              // 0 or 15
    constexpr int GXL1 = (GXL > 0) ? GXL : 1;
    constexpr int HREG = 40;                    // whh k-vals in regs
    constexpr int GHR  = HREG / 4;              // 10
    constexpr int GHL  = HH / 4 - GHR;          // 15
    constexpr int BT   = 2;                     // elems per team
    constexpr int NE   = 4;                     // elems per block

    const int tid  = threadIdx.x;               // 0..255
    const int team = tid >> 7;                  // 0..1
    const int li   = tid & 127;                 // 0..127
    const bool act = (li < HH);
    const int ii   = act ? li : 0;              // output index (clamped)
    const int e0   = team * BT;
    const int bb0  = blockIdx.x * NE;

    __shared__ __align__(16) float whh_l[3][GHL][HH][4];   // 72 KB
    __shared__ __align__(16) float wih_l[3][GXL1][HH][4];  // 72 KB or 4.8 KB
    __shared__ __align__(16) float h_s[2][NE][HH];
    __shared__ __align__(16) float x_s[2][NE][KP];

    // ---- per-thread weight registers (AGPR-resident is fine: R10/R14) ----
    float wih_r[3][XREG];
    float whh_r[3][HREG];
    float bi[3], bh[3];
    #pragma unroll
    for (int g3 = 0; g3 < 3; ++g3) {
        const int row = g3 * 100 + ii;
        #pragma unroll
        for (int k = 0; k < XREG; ++k)
            wih_r[g3][k] = (k < K) ? Wih[(long)row * K + k] : 0.f;
        #pragma unroll
        for (int k = 0; k < HREG; ++k)
            whh_r[g3][k] = Whh[(long)row * HH + k];
        bi[g3] = bih[row];
        bh[g3] = bhh[row];
    }

    // ---- stage LDS weight slices (k >= HREG / XREG), per-gate k-packed ----
    for (int idx = tid; idx < 3 * GHL * HH * 4; idx += 256) {
        int c  = idx & 3;
        int r  = (idx >> 2) % HH;
        int gg = ((idx >> 2) / HH) % GHL;
        int g3 = idx / (4 * HH * GHL);
        whh_l[g3][gg][r][c] = Whh[(long)(g3 * 100 + r) * HH + (HREG + gg * 4 + c)];
    }
    if constexpr (GXL > 0) {
        for (int idx = tid; idx < 3 * GXL * HH * 4; idx += 256) {
            int c  = idx & 3;
            int r  = (idx >> 2) % HH;
            int gg = ((idx >> 2) / HH) % GXL;
            int g3 = idx / (4 * HH * GXL);
            wih_l[g3][gg][r][c] = Wih[(long)(g3 * 100 + r) * K + (XREG + gg * 4 + c)];
        }
    }

    // ---- init h_s[0]; zero x_s (both buffers: keeps pads 0), fill x_s[0] ----
    for (int idx = tid; idx < NE * HH; idx += 256) {
        int e = idx / HH, k = idx % HH;
        h_s[0][e][k] = h_init ? h_init[(bb0 + e) * HH + k] : 0.f;
    }
    for (int idx = tid; idx < 2 * NE * KP; idx += 256)
        (&x_s[0][0][0])[idx] = 0.f;
    __syncthreads();   // x_s zero complete before t=0 fill (avoid overlap)
    for (int idx = tid; idx < NE * KP; idx += 256) {
        int e = idx / KP, k = idx % KP;
        if (k < K) {
            if constexpr (EMB) {
                int t0 = tgt[bb0 + e];
                x_s[0][e][k] = emb[t0 * K + k];
            } else {
                x_s[0][e][k] = xin[(long)(bb0 + e) * K + k];
            }
        }
    }
    __syncthreads();   // weights, h_s[0], x_s[0] ready

    int cur = 0;
    for (int t = 0; t < T; ++t) {
        const int  nxt      = cur ^ 1;
        const bool has_next = (t + 1 < T);

        // ---- prefetch next x into regs (issued early, hidden under FMAs) ----
        float px0 = 0.f, px1 = 0.f;
        if (has_next) {
            if constexpr (EMB) {
                if (tid < NE * KP) {
                    int e = tid / KP, k = tid % KP;
                    int pt = tgt[(t + 1) * TB + bb0 + e];
                    px0 = (k < K) ? emb[pt * K + k] : 0.f;
                }
            } else {
                if (tid < NE * K)
                    px0 = xin[(long)((t + 1) * TB + bb0 + tid / K) * K + tid % K];
                if constexpr (NE * K > 256) {
                    if (tid + 256 < NE * K) {
                        int idx = tid + 256;
                        px1 = xin[(long)((t + 1) * TB + bb0 + idx / K) * K + idx % K];
                    }
                }
            }
        }

        // ---- GEMVs: acc_i = bi + Wih.x ; acc_h = bh + Whh.h (k ascending) ----
        float acc_i[3][BT], acc_h[3][BT];
        #pragma unroll
        for (int g3 = 0; g3 < 3; ++g3) {
            #pragma unroll
            for (int b = 0; b < BT; ++b) { acc_i[g3][b] = bi[g3]; acc_h[g3][b] = bh[g3]; }
        }
        dot_reg<BT, KP, XREG>(std::make_index_sequence<GXR>{}, wih_r, x_s[cur], e0, acc_i);
        if constexpr (GXL > 0)
            dot_lds<GXR, BT, KP, GXL1>(std::make_index_sequence<GXL>{},
                                       wih_l, ii, x_s[cur], e0, acc_i);
        dot_reg<BT, HH, HREG>(std::make_index_sequence<GHR>{}, whh_r, h_s[cur], e0, acc_h);
        dot_lds<GHR, BT, HH, GHL>(std::make_index_sequence<GHL>{},
                                  whh_l, ii, h_s[cur], e0, acc_h);

        // ---- gates + state update (all three gates in-thread, frozen DAG) ----
        #pragma unroll
        for (int b = 0; b < BT; ++b) {
            float r  = sigmoidf_(acc_i[0][b] + acc_h[0][b]);
            float z  = sigmoidf_(acc_i[1][b] + acc_h[1][b]);
            float n  = tanhf_(acc_i[2][b] + r * acc_h[2][b]);
            float hp = h_s[cur][e0 + b][ii];
            float hn = (1.f - z) * n + z * hp;
            if (act) {
                h_s[nxt][e0 + b][li] = hn;
                if constexpr (WRITE_SEQ)
                    seq_out[((long)t * TB + bb0 + e0 + b) * HH + li] = hn;
            }
        }

        // ---- write next x (k<K only: buffer pads stay 0) ----
        if (has_next) {
            if constexpr (EMB) {
                if (tid < NE * KP) { int e = tid / KP, k = tid % KP; x_s[nxt][e][k] = px0; }
            } else {
                if (tid < NE * K) x_s[nxt][tid / K][tid % K] = px0;
                if constexpr (NE * K > 256) {
                    if (tid + 256 < NE * K) {
                        int idx = tid + 256;
                        x_s[nxt][idx / K][idx % K] = px1;
                    }
                }
            }
        }
        __syncthreads();   // single step barrier: h_s[nxt], x_s[nxt] visible
        cur = nxt;
    }

    if (h_last != nullptr && act) {
        #pragma unroll
        for (int b = 0; b < BT; ++b)
            h_last[(bb0 + e0 + b) * HH + li] = h_s[cur][e0 + b][li];
    }
}

// Final linear + argmax + target_cal.
// block = 256 = 4 slots x 64 lanes (lane = output class d, wave = one (p,b) slot)
__global__ __launch_bounds__(256)
void final_kernel(const float* __restrict__ d1,
                  const float* __restrict__ linW,   // [64,100]
                  const float* __restrict__ linb,   // [64]
                  const int*   __restrict__ tgt,    // [80,1024]
                  float* __restrict__ out0,         // [79*1024,64] logits
                  float* __restrict__ out1,         // [79*1024] target_cal
                  float* __restrict__ out2)         // [79*1024] argmax
{
    __shared__ float WT[HH][64];     // WT[k][d]
    __shared__ __align__(16) float row[4][HH];

    const int tid = threadIdx.x;
    for (int idx = tid; idx < 64 * HH; idx += 256) {
        int d = idx / HH, k = idx % HH;
        WT[k][d] = linW[idx];
    }
    const int s    = tid >> 6;
    const int d    = tid & 63;
    const int slot = blockIdx.x * 4 + s;     // < 79*1024
    const int p    = slot >> 10;
    const int b    = slot & 1023;
    const float* drow = &d1[(long)(p * TB + b) * HH];
    __syncthreads();
    if (d < 50) {
        float2 v = *reinterpret_cast<const float2*>(&drow[2 * d]);
        row[s][2 * d]     = v.x;
        row[s][2 * d + 1] = v.y;
    }
    __syncthreads();

    float acc = linb[d];
    #pragma unroll
    for (int k = 0; k < HH; ++k)
        acc += row[s][k] * WT[k][d];

    out0[(long)slot * 64 + d] = acc;

    // argmax over 64 lanes, first-occurrence tie-break (min index among maxima)
    float mv = acc;
    int   mi = d;
    #pragma unroll
    for (int off = 32; off >= 1; off >>= 1) {
        float ov = __shfl_xor(mv, off, 64);
        int   oi = __shfl_xor(mi, off, 64);
        if (ov > mv || (ov == mv && oi < mi)) { mv = ov; mi = oi; }
    }
    if (d == 0) out2[slot] = (float)mi;
    if (d == 1) out1[slot] = (float)tgt[(p + 1) * TB + b];
}

extern "C" void kernel_launch(void* const* d_in, const int* in_sizes, int n_in,
                              void* d_out, int out_size, void* d_ws, size_t ws_size,
                              hipStream_t stream)
{
    const float* x      = (const float*)d_in[0];
    const int*   target = (const int*)  d_in[1];
    const float* emb    = (const float*)d_in[2];
    const float* eWih0  = (const float*)d_in[3];
    const float* eWhh0  = (const float*)d_in[4];
    const float* ebih0  = (const float*)d_in[5];
    const float* ebhh0  = (const float*)d_in[6];
    const float* eWih1  = (const float*)d_in[7];
    const float* eWhh1  = (const float*)d_in[8];
    const float* ebih1  = (const float*)d_in[9];
    const float* ebhh1  = (const float*)d_in[10];
    const float* dWih0  = (const float*)d_in[11];
    const float* dWhh0  = (const float*)d_in[12];
    const float* dbih0  = (const float*)d_in[13];
    const float* dbhh0  = (const float*)d_in[14];
    const float* dWih1  = (const float*)d_in[15];
    const float* dWhh1  = (const float*)d_in[16];
    const float* dbih1  = (const float*)d_in[17];
    const float* dbhh1  = (const float*)d_in[18];
    const float* linW   = (const float*)d_in[19];
    const float* linb   = (const float*)d_in[20];

    // workspace layout (floats):
    //  [0, 102400)                       h_enc0
    //  [102400, 204800)                  h_enc1
    //  [204800, 204800+51.2M)            e0 during encoder
    //  same region reused for d0/d1 during decoder (e0 dead by then)
    float* ws     = (float*)d_ws;
    float* h_enc0 = ws;
    float* h_enc1 = ws + 102400;
    float* e0     = ws + 204800;                      // 500*1024*100
    float* d0     = ws + 204800;                      // aliases e0 (dead)
    float* d1_    = ws + 204800 + 80 * 1024 * 100;    // 80*1024*100

    dim3 grid(256), blk(256);
    // encoder layer 0: raw x input (K=26), write e0 + h_enc0
    gru3<26,  false, true ><<<grid, blk, 0, stream>>>(
        x, nullptr, nullptr, eWih0, eWhh0, ebih0, ebhh0, nullptr, e0, h_enc0, 500);
    // encoder layer 1: e0 input (K=100), only h_enc1 needed
    gru3<100, false, false><<<grid, blk, 0, stream>>>(
        e0, nullptr, nullptr, eWih1, eWhh1, ebih1, ebhh1, nullptr, nullptr, h_enc1, 500);
    // decoder layer 0: embedding-gather input (K=26), h0 = h_enc0
    gru3<26,  true,  true ><<<grid, blk, 0, stream>>>(
        nullptr, target, emb, dWih0, dWhh0, dbih0, dbhh0, h_enc0, d0, nullptr, 80);
    // decoder layer 1: d0 input (K=100), h0 = h_enc1, write d1
    gru3<100, false, true ><<<grid, blk, 0, stream>>>(
        d0, nullptr, nullptr, dWih1, dWhh1, dbih1, dbhh1, h_enc1, d1_, nullptr, 80);

    float* out0 = (float*)d_out;
    float* out1 = out0 + (long)79 * 1024 * 64;
    float* out2 = out1 + 79 * 1024;
    final_kernel<<<dim3(20224), dim3(256), 0, stream>>>(d1_, linW, linb, target,
                                                        out0, out1, out2);
}

// Round 6
// 34493.903 us; speedup vs baseline: 1.9245x; 1.9245x over previous
//
#include <hip/hip_runtime.h>
#include <math.h>
#include <utility>

#define TB 1024   // batch
#define HH 100    // hidden
#define GG 300    // 3*H gate rows

// ---------------------------------------------------------------------------
// NUMERICS ARE FROZEN — DO NOT TOUCH.
// Only the ocml expf/tanhf profile lands on the reference side of a
// knife-edge decoder argmax logit near-tie. The per-element expression DAG
// (values, pairing, order: acc starts at bias, ascending k, 4-term groups
// w0*x0+w1*x1+w2*x2+w3*x3) must stay bit-identical. R15's 3-gate-per-thread
// helpers (grp_reg/grp_lds) PASSED (absmax 0.0039) — lifted verbatim here.
//
// R16 model (calibrated R10-R15):
//  * Per-thread float arrays: ~100 floats -> AGPR-resident, free (R10/R14).
//    ~240 floats (R15) -> SCRATCH spill: FETCH 51.6GB, 66ms. Stay <= ~170.
//  * LDS pipe is the bottleneck: LV b128 ~12cyc, uniform b128 ~5cyc.
//    R0 enc step = 250 LV + 1000 uni ~ 8800 cyc measured.
//  * R15 structure (3 gates/thread, 1 barrier/step, h dbuf) is numerically
//    verified; only its register residency was broken.
// R16: gi = x@WihT + bih PRECOMPUTED by gemm_gi (same frozen expression,
// same zero-padding). Recurrence (gru_rec) holds only whh: 36 k in regs
// (108 floats, safe zone) + 64 k in LDS (76.8KB). gi streams from global
// (6 scalars/thread/step, prefetched). dec0: 64-row table, no gi buffer.
// ws_size-aware: enc gi chunks in tail ws if available, else fall back to
// the R0-proven gru_kernel for encoders (no-regression guarantee).
// ---------------------------------------------------------------------------
__device__ __forceinline__ float sigmoidf_(float x) {
    return 1.0f / (1.0f + expf(-x));
}
__device__ __forceinline__ float tanhf_(float x) {
    return tanhf(x);
}

template<size_t... Is>
__device__ __forceinline__ void ldN(std::index_sequence<Is...>,
                                    float* __restrict__ dst,
                                    const float* __restrict__ src) {
    ((dst[Is] = src[Is]), ...);
}
__device__ __forceinline__ float pin_val(float v) {
    asm volatile("" : "+v"(v));
    return v;
}
template<size_t... Is>
__device__ __forceinline__ void pinN(std::index_sequence<Is...>, float* w) {
    ((w[Is] = pin_val(w[Is])), ...);
}

// ======================= R15-verified 3-gate helpers =======================
// one k-group (4 values), weights from per-thread registers
template<int GGi, int BT, int LD, int NREG>
__device__ __forceinline__ void grp_reg(const float (&w)[3][NREG],
                                        const float (*vec)[LD], int e0,
                                        float (&acc)[3][BT]) {
    float4 vv[BT];
    #pragma unroll
    for (int b = 0; b < BT; ++b)
        vv[b] = *reinterpret_cast<const float4*>(&vec[e0 + b][GGi * 4]);
    #pragma unroll
    for (int g3 = 0; g3 < 3; ++g3) {
        #pragma unroll
        for (int b = 0; b < BT; ++b)
            acc[g3][b] += w[g3][GGi * 4]     * vv[b].x + w[g3][GGi * 4 + 1] * vv[b].y
                        + w[g3][GGi * 4 + 2] * vv[b].z + w[g3][GGi * 4 + 3] * vv[b].w;
    }
}
template<int BT, int LD, int NREG, size_t... Is>
__device__ __forceinline__ void dot_reg(std::index_sequence<Is...>,
                                        const float (&w)[3][NREG],
                                        const float (*vec)[LD], int e0,
                                        float (&acc)[3][BT]) {
    (grp_reg<(int)Is, BT, LD, NREG>(w, vec, e0, acc), ...);
}

// one k-group, weights from LDS [3][NG][HH][4] (k-packed per gate)
template<int GGi, int OFF, int BT, int LD, int NG>
__device__ __forceinline__ void grp_lds3(const float (&wl)[3][NG][HH][4],
                                         int ii,
                                         const float (*vec)[LD], int e0,
                                         float (&acc)[3][BT]) {
    float4 vv[BT];
    #pragma unroll
    for (int b = 0; b < BT; ++b)
        vv[b] = *reinterpret_cast<const float4*>(&vec[e0 + b][GGi * 4]);
    #pragma unroll
    for (int g3 = 0; g3 < 3; ++g3) {
        const float4 wv = *reinterpret_cast<const float4*>(wl[g3][GGi - OFF][ii]);
        #pragma unroll
        for (int b = 0; b < BT; ++b)
            acc[g3][b] += wv.x * vv[b].x + wv.y * vv[b].y
                        + wv.z * vv[b].z + wv.w * vv[b].w;
    }
}
template<int OFF, int BT, int LD, int NG, size_t... Is>
__device__ __forceinline__ void dot_lds3(std::index_sequence<Is...>,
                                         const float (&wl)[3][NG][HH][4],
                                         int ii,
                                         const float (*vec)[LD], int e0,
                                         float (&acc)[3][BT]) {
    (grp_lds3<(int)Is + OFF, OFF, BT, LD, NG>(wl, ii, vec, e0, acc), ...);
}

// ===========================================================================
// gemm_gi: gi[n, j] = bih[j] + sum_k Wih[j,k]*x[n,k]  (frozen expression:
// acc = bi, then ascending 4-term k-groups; zero-padded k>=K like the
// in-loop acc_i always was). block 320 = 3 slot-groups x 100 cols (+20 pad),
// thread owns cols {jj, 100+jj, 200+jj} x 16 slots. grid-stride over slots.
// ===========================================================================
template<int K>
__global__ __launch_bounds__(320)
void gemm_gi(const float* __restrict__ xin,  // [N, K]
             const float* __restrict__ Wih,  // [300, K]
             const float* __restrict__ bih,  // [300]
             float* __restrict__ gi,         // [N, 300]
             int N)
{
    constexpr int KP = (K + 3) & ~3;
    constexpr int NG = KP / 4;
    constexpr int SL = 48;          // slots per unit
    constexpr int SS = 16;          // slots per slot-group

    __shared__ __align__(16) float wl[3][NG][HH][4];   // 120KB (K=100) / 33.6KB
    __shared__ __align__(16) float xs[SL][KP];

    const int tid = threadIdx.x;
    const int jj  = tid % 100;
    const int sg  = tid / 100;      // 0..2 active, 3 = pad
    const bool act = (sg < 3);

    for (int idx = tid; idx < 3 * NG * HH * 4; idx += 320) {
        int c  = idx & 3;
        int r  = (idx >> 2) % HH;
        int gg = ((idx >> 2) / HH) % NG;
        int g3 = idx / (4 * HH * NG);
        int k  = gg * 4 + c;
        wl[g3][gg][r][c] = (k < K) ? Wih[(long)(g3 * 100 + r) * K + k] : 0.f;
    }
    float bi[3];
    #pragma unroll
    for (int g3 = 0; g3 < 3; ++g3) bi[g3] = bih[g3 * 100 + jj];
    __syncthreads();

    for (long c0 = (long)blockIdx.x * SL; c0 < N; c0 += (long)gridDim.x * SL) {
        for (int idx = tid; idx < SL * KP; idx += 320) {
            int s = idx / KP, k = idx % KP;
            long sl = c0 + s;
            xs[s][k] = (k < K && sl < N) ? xin[sl * K + k] : 0.f;
        }
        __syncthreads();
        if (act) {
            float acc[3][SS];
            #pragma unroll
            for (int g3 = 0; g3 < 3; ++g3)
                #pragma unroll
                for (int s = 0; s < SS; ++s) acc[g3][s] = bi[g3];
            #pragma unroll
            for (int gg = 0; gg < NG; ++gg) {
                float4 wv[3];
                #pragma unroll
                for (int g3 = 0; g3 < 3; ++g3)
                    wv[g3] = *reinterpret_cast<const float4*>(wl[g3][gg][jj]);
                #pragma unroll
                for (int s = 0; s < SS; ++s) {
                    const float4 xv =
                        *reinterpret_cast<const float4*>(&xs[sg * SS + s][gg * 4]);
                    #pragma unroll
                    for (int g3 = 0; g3 < 3; ++g3)
                        acc[g3][s] += wv[g3].x * xv.x + wv[g3].y * xv.y
                                    + wv[g3].z * xv.z + wv[g3].w * xv.w;
                }
            }
            #pragma unroll
            for (int s = 0; s < SS; ++s) {
                long sl = c0 + sg * SS + s;
                if (sl < N) {
                    #pragma unroll
                    for (int g3 = 0; g3 < 3; ++g3)
                        gi[sl * 300 + g3 * 100 + jj] = acc[g3][s];
                }
            }
        }
        __syncthreads();   // xs reuse guard
    }
}

// ===========================================================================
// gru_rec: h-recurrence only (gi precomputed). Block 256 = 2 teams x 128;
// thread owns gate-rows {ii,100+ii,200+ii}; BT=2 elems/team, NE=4/block,
// grid 256 (1 block/CU, full batch resident). whh: k<36 in regs (108 floats,
// safe), k>=36 in LDS (76.8KB). One barrier/step; h double-buffered.
// EMB: gi read as table[tgt[t,b]] (table = emb@WihT+bih, 64 rows).
// ===========================================================================
template<bool EMB, bool WRITE_SEQ>
__global__ __launch_bounds__(256)
void gru_rec(const float* __restrict__ gi,    // [t1-t0, B, 300] (if !EMB)
             const int*   __restrict__ tgt,   // [Tfull, B]      (if EMB)
             const float* __restrict__ table, // [64, 300]       (if EMB)
             const float* __restrict__ Whh,   // [300,100]
             const float* __restrict__ bhh,   // [300]
             const float* __restrict__ h_init,// [B,100] or null -> zeros
             float* __restrict__ seq_out,     // [Tfull,B,100] (if WRITE_SEQ)
             float* __restrict__ h_last,      // [B,100] or null
             int t0, int t1)
{
    constexpr int HREG = 36;             // whh k-values in registers
    constexpr int GHR  = HREG / 4;       // 9
    constexpr int GHL  = HH / 4 - GHR;   // 16
    constexpr int BT   = 2;
    constexpr int NE   = 4;

    const int tid  = threadIdx.x;
    const int team = tid >> 7;
    const int li   = tid & 127;
    const bool act = (li < HH);
    const int ii   = act ? li : 0;
    const int e0i  = team * BT;
    const int bb0  = blockIdx.x * NE;

    __shared__ __align__(16) float whh_l[3][GHL][HH][4];   // 76800 B
    __shared__ __align__(16) float h_s[2][NE][HH];         // 3200 B

    // ---- whh k<36 rows into regs (108 floats: proven-safe residency) ----
    float whr[3][HREG];
    float bh[3];
    #pragma unroll
    for (int g3 = 0; g3 < 3; ++g3) {
        const int row = g3 * 100 + ii;
        #pragma unroll
        for (int k = 0; k < HREG; ++k)
            whr[g3][k] = Whh[(long)row * HH + k];
        bh[g3] = bhh[row];
    }
    // ---- stage whh k>=36 into LDS, per-gate k-packed ----
    for (int idx = tid; idx < 3 * GHL * HH * 4; idx += 256) {
        int c  = idx & 3;
        int r  = (idx >> 2) % HH;
        int gg = ((idx >> 2) / HH) % GHL;
        int g3 = idx / (4 * HH * GHL);
        whh_l[g3][gg][r][c] = Whh[(long)(g3 * 100 + r) * HH + (HREG + gg * 4 + c)];
    }
    // ---- init h ----
    for (int idx = tid; idx < NE * HH; idx += 256) {
        int e = idx / HH, k = idx % HH;
        h_s[0][e][k] = h_init ? h_init[(bb0 + e) * HH + k] : 0.f;
    }
    // ---- initial gi (t0) ----
    float gcur[3][BT];
    #pragma unroll
    for (int b = 0; b < BT; ++b) {
        const int e = e0i + b;
        const float* base;
        if constexpr (EMB) {
            base = table + (long)tgt[t0 * TB + bb0 + e] * 300;
        } else {
            base = gi + (long)(bb0 + e) * 300;   // (t0-t0)=0
        }
        #pragma unroll
        for (int g3 = 0; g3 < 3; ++g3) gcur[g3][b] = base[g3 * 100 + ii];
    }
    __syncthreads();   // whh_l, h_s[0] ready

    int cur = 0;
    for (int t = t0; t < t1; ++t) {
        const int nxt = cur ^ 1;

        // ---- prefetch next-step gi (hidden under the dot) ----
        float gnxt[3][BT] = {};
        if (t + 1 < t1) {
            #pragma unroll
            for (int b = 0; b < BT; ++b) {
                const int e = e0i + b;
                const float* base;
                if constexpr (EMB) {
                    base = table + (long)tgt[(t + 1) * TB + bb0 + e] * 300;
                } else {
                    base = gi + ((long)(t + 1 - t0) * TB + bb0 + e) * 300;
                }
                #pragma unroll
                for (int g3 = 0; g3 < 3; ++g3) gnxt[g3][b] = base[g3 * 100 + ii];
            }
        }

        // ---- acc_h = bh + Whh.h (ascending k: 9 reg groups, 16 LDS groups) ----
        float acc[3][BT];
        #pragma unroll
        for (int g3 = 0; g3 < 3; ++g3)
            #pragma unroll
            for (int b = 0; b < BT; ++b) acc[g3][b] = bh[g3];
        dot_reg<BT, HH, HREG>(std::make_index_sequence<GHR>{}, whr,
                              h_s[cur], e0i, acc);
        dot_lds3<GHR, BT, HH, GHL>(std::make_index_sequence<GHL>{}, whh_l, ii,
                                   h_s[cur], e0i, acc);

        // ---- gates + state update (R15-verified frozen DAG) ----
        #pragma unroll
        for (int b = 0; b < BT; ++b) {
            float r  = sigmoidf_(gcur[0][b] + acc[0][b]);
            float z  = sigmoidf_(gcur[1][b] + acc[1][b]);
            float n  = tanhf_(gcur[2][b] + r * acc[2][b]);
            float hp = h_s[cur][e0i + b][ii];
            float hn = (1.f - z) * n + z * hp;
            if (act) {
                h_s[nxt][e0i + b][li] = hn;
                if constexpr (WRITE_SEQ)
                    seq_out[((long)t * TB + bb0 + e0i + b) * HH + li] = hn;
            }
        }
        __syncthreads();   // single step barrier: h_s[nxt] visible
        #pragma unroll
        for (int g3 = 0; g3 < 3; ++g3)
            #pragma unroll
            for (int b = 0; b < BT; ++b) gcur[g3][b] = gnxt[g3][b];
        cur = nxt;
    }

    if (h_last != nullptr && act) {
        #pragma unroll
        for (int b = 0; b < BT; ++b)
            h_last[(bb0 + e0i + b) * HH + li] = h_s[cur][e0i + b][li];
    }
}

// ===========================================================================
// FALLBACK: R0's proven gru_kernel (verbatim; 1797/1841 us) for encoders
// when ws has no room for gi chunks.
// ===========================================================================
template<int KK, int BT, int LD>
__device__ __forceinline__ void fma_step(const float* __restrict__ w,
                                         const float (*xs)[LD],
                                         float* __restrict__ acc) {
    #pragma unroll
    for (int b = 0; b < BT; ++b) {
        const float4 xv = *reinterpret_cast<const float4*>(&xs[b][KK]);
        acc[b] += w[KK]     * xv.x + w[KK + 1] * xv.y
                + w[KK + 2] * xv.z + w[KK + 3] * xv.w;
    }
}
template<int BT, int LD, size_t... Is>
__device__ __forceinline__ void gemv4(std::index_sequence<Is...>,
                                      const float* __restrict__ w,
                                      const float (*xs)[LD],
                                      float* __restrict__ acc) {
    (fma_step<(int)(Is * 4), BT, LD>(w, xs, acc), ...);
}
template<int GRP, int BT>
__device__ __forceinline__ void fma_lds_step(const float* __restrict__ wl,
                                             int row,
                                             const float (*hs)[HH],
                                             float* __restrict__ acc) {
    const float4 wv = *reinterpret_cast<const float4*>(wl + (GRP * GG + row) * 4);
    #pragma unroll
    for (int b = 0; b < BT; ++b) {
        const float4 hv = *reinterpret_cast<const float4*>(&hs[b][GRP * 4]);
        acc[b] += wv.x * hv.x + wv.y * hv.y + wv.z * hv.z + wv.w * hv.w;
    }
}
template<int BT, size_t... Is>
__device__ __forceinline__ void gemv_lds(std::index_sequence<Is...>,
                                         const float* __restrict__ wl, int row,
                                         const float (*hs)[HH],
                                         float* __restrict__ acc) {
    (fma_lds_step<(int)Is, BT>(wl, row, hs, acc), ...);
}

template<int K, bool EMB, bool WRITE_SEQ>
__global__ __launch_bounds__(640, 3)
void gru_old(const float* __restrict__ xin,
             const int*   __restrict__ tgt,
             const float* __restrict__ emb,
             const float* __restrict__ Wih,
             const float* __restrict__ Whh,
             const float* __restrict__ bih,
             const float* __restrict__ bhh,
             const float* __restrict__ h_init,
             float* __restrict__ seq_out,
             float* __restrict__ h_last,
             int T)
{
    constexpr int KP = (K + 3) & ~3;
    constexpr int BT = 2;
    constexpr int NT = 2;
    static_assert(KP % 4 == 0, "");

    const int tid  = threadIdx.x;
    const int team = tid / 320;
    const int tj   = tid % 320;
    const int bb0  = blockIdx.x * (BT * NT) + team * BT;
    const int g    = tj / 100;
    const int i    = tj % 100;

    __shared__ __align__(16) float whh_l[(HH / 4) * GG * 4];
    __shared__ __align__(16) float h_s[NT][BT][HH];
    __shared__ __align__(16) float x_s[NT][BT][KP];
    __shared__ float r_s[NT][BT][HH];
    __shared__ float z_s[NT][BT][HH];
    __shared__ float emb_s[EMB ? 64 : 1][EMB ? 28 : 4];
    __shared__ int   tgt_s[NT * BT];

    const int jj = (tj < GG) ? tj : 0;
    float wih[KP];
    ldN(std::make_index_sequence<K>{}, wih, Wih + (long)jj * K);
    #pragma unroll
    for (int k = K; k < KP; ++k) wih[k] = 0.f;
    float bi = bih[jj];
    float bh = bhh[jj];

    for (int idx = tid; idx < GG * HH; idx += 640) {
        int row = idx / HH, k = idx % HH;
        whh_l[((k >> 2) * GG + row) * 4 + (k & 3)] = Whh[row * HH + k];
    }
    for (int idx = tj; idx < BT * HH; idx += 320) {
        int b = idx / HH, k = idx % HH;
        h_s[team][b][k] = h_init ? h_init[(bb0 + b) * HH + k] : 0.f;
    }
    if constexpr (EMB) {
        for (int idx = tid; idx < 64 * 28; idx += 640) {
            int d = idx / 28, k = idx % 28;
            emb_s[d][k] = (k < 26) ? emb[d * 26 + k] : 0.f;
        }
        __syncthreads();
        for (int idx = tj; idx < BT * KP; idx += 320) {
            int b = idx / KP, k = idx % KP;
            int t0 = tgt[bb0 + b];
            x_s[team][b][k] = emb_s[t0][k];
        }
    } else {
        for (int idx = tj; idx < BT * KP; idx += 320) {
            int b = idx / KP, k = idx % KP;
            x_s[team][b][k] = (k < K) ? xin[(bb0 + b) * K + k] : 0.f;
        }
    }
    __syncthreads();

    for (int t = 0; t < T; ++t) {
        pinN(std::make_index_sequence<KP>{}, wih);
        bi = pin_val(bi);
        bh = pin_val(bh);

        const bool has_next = (t + 1 < T);
        float px = 0.f;
        int   ptg = 0;
        if constexpr (!EMB) {
            if (has_next && !(tj >= 200 && tj < 300)) {
                int stid = (tj < 200) ? tj : tj - 100;
                if (stid < BT * K)
                    px = xin[((t + 1) * TB + bb0 + stid / K) * K + stid % K];
            }
        } else {
            if (has_next && tj < BT) ptg = tgt[(t + 1) * TB + bb0 + tj];
        }

        float acc_i[BT], acc_h[BT];
        #pragma unroll
        for (int b = 0; b < BT; ++b) { acc_i[b] = bi; acc_h[b] = bh; }

        gemv4<BT, KP>(std::make_index_sequence<KP / 4>{}, wih, x_s[team], acc_i);
        gemv_lds<BT>(std::make_index_sequence<HH / 4>{}, whh_l, jj, h_s[team], acc_h);

        if (tj < 200) {
            #pragma unroll
            for (int b = 0; b < BT; ++b) {
                float v = sigmoidf_(acc_i[b] + acc_h[b]);
                if (g == 0) r_s[team][b][i] = v;
                else        z_s[team][b][i] = v;
            }
        }
        __syncthreads();

        if (tj >= 200 && tj < 300) {
            #pragma unroll
            for (int b = 0; b < BT; ++b) {
                float n  = tanhf_(acc_i[b] + r_s[team][b][i] * acc_h[b]);
                float z  = z_s[team][b][i];
                float hn = (1.f - z) * n + z * h_s[team][b][i];
                h_s[team][b][i] = hn;
                if (WRITE_SEQ)
                    seq_out[((long)t * TB + bb0 + b) * HH + i] = hn;
            }
        } else if constexpr (!EMB) {
            if (has_next) {
                int stid = (tj < 200) ? tj : tj - 100;
                if (stid < BT * K) x_s[team][stid / K][stid % K] = px;
            }
        }
        if constexpr (EMB) {
            if (has_next && tj < BT) tgt_s[team * BT + tj] = ptg;
            __syncthreads();
            if (has_next && tj < BT * KP) {
                int b = tj / KP, k = tj % KP;
                x_s[team][b][k] = emb_s[tgt_s[team * BT + b]][k];
            }
        }
        __syncthreads();
    }

    if (h_last != nullptr && tj >= 200 && tj < 300) {
        #pragma unroll
        for (int b = 0; b < BT; ++b)
            h_last[(bb0 + b) * HH + i] = h_s[team][b][i];
    }
}

// Final linear + argmax + target_cal.
__global__ __launch_bounds__(256)
void final_kernel(const float* __restrict__ d1,
                  const float* __restrict__ linW,   // [64,100]
                  const float* __restrict__ linb,   // [64]
                  const int*   __restrict__ tgt,    // [80,1024]
                  float* __restrict__ out0,         // [79*1024,64] logits
                  float* __restrict__ out1,         // [79*1024] target_cal
                  float* __restrict__ out2)         // [79*1024] argmax
{
    __shared__ float WT[HH][64];
    __shared__ __align__(16) float row[4][HH];

    const int tid = threadIdx.x;
    for (int idx = tid; idx < 64 * HH; idx += 256) {
        int d = idx / HH, k = idx % HH;
        WT[k][d] = linW[idx];
    }
    const int s    = tid >> 6;
    const int d    = tid & 63;
    const int slot = blockIdx.x * 4 + s;
    const int p    = slot >> 10;
    const int b    = slot & 1023;
    const float* drow = &d1[(long)(p * TB + b) * HH];
    __syncthreads();
    if (d < 50) {
        float2 v = *reinterpret_cast<const float2*>(&drow[2 * d]);
        row[s][2 * d]     = v.x;
        row[s][2 * d + 1] = v.y;
    }
    __syncthreads();

    float acc = linb[d];
    #pragma unroll
    for (int k = 0; k < HH; ++k)
        acc += row[s][k] * WT[k][d];

    out0[(long)slot * 64 + d] = acc;

    float mv = acc;
    int   mi = d;
    #pragma unroll
    for (int off = 32; off >= 1; off >>= 1) {
        float ov = __shfl_xor(mv, off, 64);
        int   oi = __shfl_xor(mi, off, 64);
        if (ov > mv || (ov == mv && oi < mi)) { mv = ov; mi = oi; }
    }
    if (d == 0) out2[slot] = (float)mi;
    if (d == 1) out1[slot] = (float)tgt[(p + 1) * TB + b];
}

extern "C" void kernel_launch(void* const* d_in, const int* in_sizes, int n_in,
                              void* d_out, int out_size, void* d_ws, size_t ws_size,
                              hipStream_t stream)
{
    const float* x      = (const float*)d_in[0];
    const int*   target = (const int*)  d_in[1];
    const float* emb    = (const float*)d_in[2];
    const float* eWih0  = (const float*)d_in[3];
    const float* eWhh0  = (const float*)d_in[4];
    const float* ebih0  = (const float*)d_in[5];
    const float* ebhh0  = (const float*)d_in[6];
    const float* eWih1  = (const float*)d_in[7];
    const float* eWhh1  = (const float*)d_in[8];
    const float* ebih1  = (const float*)d_in[9];
    const float* ebhh1  = (const float*)d_in[10];
    const float* dWih0  = (const float*)d_in[11];
    const float* dWhh0  = (const float*)d_in[12];
    const float* dbih0  = (const float*)d_in[13];
    const float* dbhh0  = (const float*)d_in[14];
    const float* dWih1  = (const float*)d_in[15];
    const float* dWhh1  = (const float*)d_in[16];
    const float* dbih1  = (const float*)d_in[17];
    const float* dbhh1  = (const float*)d_in[18];
    const float* linW   = (const float*)d_in[19];
    const float* linb   = (const float*)d_in[20];

    // workspace layout (floats):
    //  [0, 102400)              h_enc0 (persistent h for enc0 chunks, then dec0 h0)
    //  [102400, 204800)         h_enc1
    //  [204800, 51,404,800)     e0 (enc phase). Decoder phase (e0 dead):
    //      d0     = e0                       [204800, 8,396,800)
    //      d1_    = e0 + 8,192,000           [8,396,800, 16,588,800)
    //      gi_dec = e0 + 16,384,000          [16,588,800, 41,164,800)
    //      table  = e0 + 40,960,000          [41,164,800, 41,184,000)
    //  [51,404,800, ...)        gi_enc chunk tail (if ws_size permits)
    float* ws     = (float*)d_ws;
    float* h_enc0 = ws;
    float* h_enc1 = ws + 102400;
    float* e0     = ws + 204800;
    float* d0     = e0;
    float* d1_    = e0 + 8192000;
    float* gi_dec = e0 + 16384000;
    float* table  = e0 + 40960000;
    float* gi_enc = ws + 51404800;

    long ws_floats = (long)(ws_size / 4);
    long avail     = ws_floats - 51404800L;
    long Cmax      = (avail > 0) ? avail / 307200L : 0;     // enc gi steps per chunk
    int  C         = (int)((Cmax > 500) ? 500 : Cmax);
    const bool use_gi = (C >= 50);

    dim3 gG(256), gB(320);        // gemm_gi
    dim3 rG(256), rB(256);        // gru_rec

    if (use_gi) {
        // encoder layer 0 (K=26): gemm chunks -> rec chunks, h in h_enc0
        for (int c0 = 0; c0 < 500; c0 += C) {
            int Cc = (500 - c0 < C) ? (500 - c0) : C;
            gemm_gi<26><<<gG, gB, 0, stream>>>(
                x + (long)c0 * TB * 26, eWih0, ebih0, gi_enc, Cc * TB);
            gru_rec<false, true><<<rG, rB, 0, stream>>>(
                gi_enc, nullptr, nullptr, eWhh0, ebhh0,
                c0 ? h_enc0 : nullptr, e0, h_enc0, c0, c0 + Cc);
        }
        // encoder layer 1 (K=100): reads e0 chunkwise, h in h_enc1
        for (int c0 = 0; c0 < 500; c0 += C) {
            int Cc = (500 - c0 < C) ? (500 - c0) : C;
            gemm_gi<100><<<gG, gB, 0, stream>>>(
                e0 + (long)c0 * TB * 100, eWih1, ebih1, gi_enc, Cc * TB);
            gru_rec<false, false><<<rG, rB, 0, stream>>>(
                gi_enc, nullptr, nullptr, eWhh1, ebhh1,
                c0 ? h_enc1 : nullptr, nullptr, h_enc1, c0, c0 + Cc);
        }
    } else {
        // fallback: proven R0 kernels (no extra ws needed)
        gru_old<26,  false, true ><<<dim3(256), dim3(640), 0, stream>>>(
            x, nullptr, nullptr, eWih0, eWhh0, ebih0, ebhh0, nullptr, e0, h_enc0, 500);
        gru_old<100, false, false><<<dim3(256), dim3(640), 0, stream>>>(
            e0, nullptr, nullptr, eWih1, eWhh1, ebih1, ebhh1, nullptr, nullptr, h_enc1, 500);
    }

    // decoder layer 0 (K=26, EMB): 64-row gi table, no gi buffer
    gemm_gi<26><<<gG, gB, 0, stream>>>(emb, dWih0, dbih0, table, 64);
    gru_rec<true, true><<<rG, rB, 0, stream>>>(
        nullptr, target, table, dWhh0, dbhh0, h_enc0, d0, nullptr, 0, 80);

    // decoder layer 1 (K=100): full gi fits inside dead e0 region
    gemm_gi<100><<<gG, gB, 0, stream>>>(d0, dWih1, dbih1, gi_dec, 80 * TB);
    gru_rec<false, true><<<rG, rB, 0, stream>>>(
        gi_dec, nullptr, nullptr, dWhh1, dbhh1, h_enc1, d1_, nullptr, 0, 80);

    float* out0 = (float*)d_out;
    float* out1 = out0 + (long)79 * 1024 * 64;
    float* out2 = out1 + 79 * 1024;
    final_kernel<<<dim3(20224), dim3(256), 0, stream>>>(d1_, linW, linb, target,
                                                        out0, out1, out2);
}

// Round 7
// 31978.665 us; speedup vs baseline: 2.0759x; 1.0787x over previous
//
#include <hip/hip_runtime.h>
#include <math.h>
#include <utility>

#define TB 1024   // batch
#define HH 100    // hidden
#define GG 300    // 3*H gate rows

// ---------------------------------------------------------------------------
// NUMERICS ARE FROZEN — DO NOT TOUCH.
// Only the ocml expf/tanhf profile lands on the reference side of a
// knife-edge decoder argmax logit near-tie. The per-element expression DAG
// (values, pairing, order: acc starts at bias, ascending k, 4-term groups
// w0*x0+w1*x1+w2*x2+w3*x3) must stay bit-identical. The gemm+rec split was
// VERIFIED in R16 (passed, absmax 0.0039) — structure kept byte-identical.
//
// REGISTER LAW (calibrated R10-R16): plain launch_bounds -> 128 arch-VGPR
// cap; per-thread live floats must stay <~110 or the allocator spills to
// SCRATCH (R15: 66ms; R16 gemm acc[3][16]: FETCH 4.9GB/dispatch, 34ms).
// R17: gemm_gi re-blocked SS 16->12 (acc 36 + wv 12 + xv ~= 95 live, fits).
// Everything else identical to R16.
// ---------------------------------------------------------------------------
__device__ __forceinline__ float sigmoidf_(float x) {
    return 1.0f / (1.0f + expf(-x));
}
__device__ __forceinline__ float tanhf_(float x) {
    return tanhf(x);
}

template<size_t... Is>
__device__ __forceinline__ void ldN(std::index_sequence<Is...>,
                                    float* __restrict__ dst,
                                    const float* __restrict__ src) {
    ((dst[Is] = src[Is]), ...);
}
__device__ __forceinline__ float pin_val(float v) {
    asm volatile("" : "+v"(v));
    return v;
}
template<size_t... Is>
__device__ __forceinline__ void pinN(std::index_sequence<Is...>, float* w) {
    ((w[Is] = pin_val(w[Is])), ...);
}

// ======================= R15/R16-verified 3-gate helpers ====================
template<int GGi, int BT, int LD, int NREG>
__device__ __forceinline__ void grp_reg(const float (&w)[3][NREG],
                                        const float (*vec)[LD], int e0,
                                        float (&acc)[3][BT]) {
    float4 vv[BT];
    #pragma unroll
    for (int b = 0; b < BT; ++b)
        vv[b] = *reinterpret_cast<const float4*>(&vec[e0 + b][GGi * 4]);
    #pragma unroll
    for (int g3 = 0; g3 < 3; ++g3) {
        #pragma unroll
        for (int b = 0; b < BT; ++b)
            acc[g3][b] += w[g3][GGi * 4]     * vv[b].x + w[g3][GGi * 4 + 1] * vv[b].y
                        + w[g3][GGi * 4 + 2] * vv[b].z + w[g3][GGi * 4 + 3] * vv[b].w;
    }
}
template<int BT, int LD, int NREG, size_t... Is>
__device__ __forceinline__ void dot_reg(std::index_sequence<Is...>,
                                        const float (&w)[3][NREG],
                                        const float (*vec)[LD], int e0,
                                        float (&acc)[3][BT]) {
    (grp_reg<(int)Is, BT, LD, NREG>(w, vec, e0, acc), ...);
}

template<int GGi, int OFF, int BT, int LD, int NG>
__device__ __forceinline__ void grp_lds3(const float (&wl)[3][NG][HH][4],
                                         int ii,
                                         const float (*vec)[LD], int e0,
                                         float (&acc)[3][BT]) {
    float4 vv[BT];
    #pragma unroll
    for (int b = 0; b < BT; ++b)
        vv[b] = *reinterpret_cast<const float4*>(&vec[e0 + b][GGi * 4]);
    #pragma unroll
    for (int g3 = 0; g3 < 3; ++g3) {
        const float4 wv = *reinterpret_cast<const float4*>(wl[g3][GGi - OFF][ii]);
        #pragma unroll
        for (int b = 0; b < BT; ++b)
            acc[g3][b] += wv.x * vv[b].x + wv.y * vv[b].y
                        + wv.z * vv[b].z + wv.w * vv[b].w;
    }
}
template<int OFF, int BT, int LD, int NG, size_t... Is>
__device__ __forceinline__ void dot_lds3(std::index_sequence<Is...>,
                                         const float (&wl)[3][NG][HH][4],
                                         int ii,
                                         const float (*vec)[LD], int e0,
                                         float (&acc)[3][BT]) {
    (grp_lds3<(int)Is + OFF, OFF, BT, LD, NG>(wl, ii, vec, e0, acc), ...);
}

// ===========================================================================
// gemm_gi: gi[n, j] = bih[j] + sum_k Wih[j,k]*x[n,k]  (frozen expression:
// acc = bi, then ascending 4-term k-groups; zero-padded k>=K).
// block 320 = 3 slot-groups x 100 cols (+20 pad). SS=12 slots per group
// (acc[3][12]=36 regs + wv 12 -> ~95 live, fits the 128 cap; R16's SS=16
// spilled to scratch). grid-stride over slot units of SL=36.
// ===========================================================================
template<int K>
__global__ __launch_bounds__(320)
void gemm_gi(const float* __restrict__ xin,  // [N, K]
             const float* __restrict__ Wih,  // [300, K]
             const float* __restrict__ bih,  // [300]
             float* __restrict__ gi,         // [N, 300]
             int N)
{
    constexpr int KP = (K + 3) & ~3;
    constexpr int NG = KP / 4;
    constexpr int SS = 12;          // slots per slot-group
    constexpr int SL = 3 * SS;      // slots per unit = 36

    __shared__ __align__(16) float wl[3][NG][HH][4];   // 120KB (K=100) / 33.6KB
    __shared__ __align__(16) float xs[SL][KP];         // 14.4KB / 4KB

    const int tid = threadIdx.x;
    const int jj  = tid % 100;
    const int sg  = tid / 100;      // 0..2 active, 3 = pad
    const bool act = (sg < 3);

    for (int idx = tid; idx < 3 * NG * HH * 4; idx += 320) {
        int c  = idx & 3;
        int r  = (idx >> 2) % HH;
        int gg = ((idx >> 2) / HH) % NG;
        int g3 = idx / (4 * HH * NG);
        int k  = gg * 4 + c;
        wl[g3][gg][r][c] = (k < K) ? Wih[(long)(g3 * 100 + r) * K + k] : 0.f;
    }
    float bi[3];
    #pragma unroll
    for (int g3 = 0; g3 < 3; ++g3) bi[g3] = bih[g3 * 100 + jj];
    __syncthreads();

    for (long c0 = (long)blockIdx.x * SL; c0 < N; c0 += (long)gridDim.x * SL) {
        for (int idx = tid; idx < SL * KP; idx += 320) {
            int s = idx / KP, k = idx % KP;
            long sl = c0 + s;
            xs[s][k] = (k < K && sl < N) ? xin[sl * K + k] : 0.f;
        }
        __syncthreads();
        if (act) {
            float acc[3][SS];
            #pragma unroll
            for (int g3 = 0; g3 < 3; ++g3)
                #pragma unroll
                for (int s = 0; s < SS; ++s) acc[g3][s] = bi[g3];
            #pragma unroll
            for (int gg = 0; gg < NG; ++gg) {
                float4 wv[3];
                #pragma unroll
                for (int g3 = 0; g3 < 3; ++g3)
                    wv[g3] = *reinterpret_cast<const float4*>(wl[g3][gg][jj]);
                #pragma unroll
                for (int s = 0; s < SS; ++s) {
                    const float4 xv =
                        *reinterpret_cast<const float4*>(&xs[sg * SS + s][gg * 4]);
                    #pragma unroll
                    for (int g3 = 0; g3 < 3; ++g3)
                        acc[g3][s] += wv[g3].x * xv.x + wv[g3].y * xv.y
                                    + wv[g3].z * xv.z + wv[g3].w * xv.w;
                }
            }
            #pragma unroll
            for (int s = 0; s < SS; ++s) {
                long sl = c0 + sg * SS + s;
                if (sl < N) {
                    #pragma unroll
                    for (int g3 = 0; g3 < 3; ++g3)
                        gi[sl * 300 + g3 * 100 + jj] = acc[g3][s];
                }
            }
        }
        __syncthreads();   // xs reuse guard
    }
}

// ===========================================================================
// gru_rec: h-recurrence only (gi precomputed). Block 256 = 2 teams x 128;
// thread owns gate-rows {ii,100+ii,200+ii}; BT=2 elems/team, NE=4/block,
// grid 256. whh: k<36 in regs (108 floats, safe) + k>=36 in LDS (76.8KB).
// One barrier/step; h double-buffered. VERIFIED in R16.
// ===========================================================================
template<bool EMB, bool WRITE_SEQ>
__global__ __launch_bounds__(256)
void gru_rec(const float* __restrict__ gi,    // [t1-t0, B, 300] (if !EMB)
             const int*   __restrict__ tgt,   // [Tfull, B]      (if EMB)
             const float* __restrict__ table, // [64, 300]       (if EMB)
             const float* __restrict__ Whh,   // [300,100]
             const float* __restrict__ bhh,   // [300]
             const float* __restrict__ h_init,// [B,100] or null -> zeros
             float* __restrict__ seq_out,     // [Tfull,B,100] (if WRITE_SEQ)
             float* __restrict__ h_last,      // [B,100] or null
             int t0, int t1)
{
    constexpr int HREG = 36;
    constexpr int GHR  = HREG / 4;       // 9
    constexpr int GHL  = HH / 4 - GHR;   // 16
    constexpr int BT   = 2;
    constexpr int NE   = 4;

    const int tid  = threadIdx.x;
    const int team = tid >> 7;
    const int li   = tid & 127;
    const bool act = (li < HH);
    const int ii   = act ? li : 0;
    const int e0i  = team * BT;
    const int bb0  = blockIdx.x * NE;

    __shared__ __align__(16) float whh_l[3][GHL][HH][4];   // 76800 B
    __shared__ __align__(16) float h_s[2][NE][HH];

    float whr[3][HREG];
    float bh[3];
    #pragma unroll
    for (int g3 = 0; g3 < 3; ++g3) {
        const int row = g3 * 100 + ii;
        #pragma unroll
        for (int k = 0; k < HREG; ++k)
            whr[g3][k] = Whh[(long)row * HH + k];
        bh[g3] = bhh[row];
    }
    for (int idx = tid; idx < 3 * GHL * HH * 4; idx += 256) {
        int c  = idx & 3;
        int r  = (idx >> 2) % HH;
        int gg = ((idx >> 2) / HH) % GHL;
        int g3 = idx / (4 * HH * GHL);
        whh_l[g3][gg][r][c] = Whh[(long)(g3 * 100 + r) * HH + (HREG + gg * 4 + c)];
    }
    for (int idx = tid; idx < NE * HH; idx += 256) {
        int e = idx / HH, k = idx % HH;
        h_s[0][e][k] = h_init ? h_init[(bb0 + e) * HH + k] : 0.f;
    }
    float gcur[3][BT];
    #pragma unroll
    for (int b = 0; b < BT; ++b) {
        const int e = e0i + b;
        const float* base;
        if constexpr (EMB) {
            base = table + (long)tgt[t0 * TB + bb0 + e] * 300;
        } else {
            base = gi + (long)(bb0 + e) * 300;
        }
        #pragma unroll
        for (int g3 = 0; g3 < 3; ++g3) gcur[g3][b] = base[g3 * 100 + ii];
    }
    __syncthreads();

    int cur = 0;
    for (int t = t0; t < t1; ++t) {
        const int nxt = cur ^ 1;

        float gnxt[3][BT] = {};
        if (t + 1 < t1) {
            #pragma unroll
            for (int b = 0; b < BT; ++b) {
                const int e = e0i + b;
                const float* base;
                if constexpr (EMB) {
                    base = table + (long)tgt[(t + 1) * TB + bb0 + e] * 300;
                } else {
                    base = gi + ((long)(t + 1 - t0) * TB + bb0 + e) * 300;
                }
                #pragma unroll
                for (int g3 = 0; g3 < 3; ++g3) gnxt[g3][b] = base[g3 * 100 + ii];
            }
        }

        float acc[3][BT];
        #pragma unroll
        for (int g3 = 0; g3 < 3; ++g3)
            #pragma unroll
            for (int b = 0; b < BT; ++b) acc[g3][b] = bh[g3];
        dot_reg<BT, HH, HREG>(std::make_index_sequence<GHR>{}, whr,
                              h_s[cur], e0i, acc);
        dot_lds3<GHR, BT, HH, GHL>(std::make_index_sequence<GHL>{}, whh_l, ii,
                                   h_s[cur], e0i, acc);

        #pragma unroll
        for (int b = 0; b < BT; ++b) {
            float r  = sigmoidf_(gcur[0][b] + acc[0][b]);
            float z  = sigmoidf_(gcur[1][b] + acc[1][b]);
            float n  = tanhf_(gcur[2][b] + r * acc[2][b]);
            float hp = h_s[cur][e0i + b][ii];
            float hn = (1.f - z) * n + z * hp;
            if (act) {
                h_s[nxt][e0i + b][li] = hn;
                if constexpr (WRITE_SEQ)
                    seq_out[((long)t * TB + bb0 + e0i + b) * HH + li] = hn;
            }
        }
        __syncthreads();
        #pragma unroll
        for (int g3 = 0; g3 < 3; ++g3)
            #pragma unroll
            for (int b = 0; b < BT; ++b) gcur[g3][b] = gnxt[g3][b];
        cur = nxt;
    }

    if (h_last != nullptr && act) {
        #pragma unroll
        for (int b = 0; b < BT; ++b)
            h_last[(bb0 + e0i + b) * HH + li] = h_s[cur][e0i + b][li];
    }
}

// ===========================================================================
// FALLBACK: R0's proven gru_kernel (verbatim) for encoders when ws has no
// room for gi chunks.
// ===========================================================================
template<int KK, int BT, int LD>
__device__ __forceinline__ void fma_step(const float* __restrict__ w,
                                         const float (*xs)[LD],
                                         float* __restrict__ acc) {
    #pragma unroll
    for (int b = 0; b < BT; ++b) {
        const float4 xv = *reinterpret_cast<const float4*>(&xs[b][KK]);
        acc[b] += w[KK]     * xv.x + w[KK + 1] * xv.y
                + w[KK + 2] * xv.z + w[KK + 3] * xv.w;
    }
}
template<int BT, int LD, size_t... Is>
__device__ __forceinline__ void gemv4(std::index_sequence<Is...>,
                                      const float* __restrict__ w,
                                      const float (*xs)[LD],
                                      float* __restrict__ acc) {
    (fma_step<(int)(Is * 4), BT, LD>(w, xs, acc), ...);
}
template<int GRP, int BT>
__device__ __forceinline__ void fma_lds_step(const float* __restrict__ wl,
                                             int row,
                                             const float (*hs)[HH],
                                             float* __restrict__ acc) {
    const float4 wv = *reinterpret_cast<const float4*>(wl + (GRP * GG + row) * 4);
    #pragma unroll
    for (int b = 0; b < BT; ++b) {
        const float4 hv = *reinterpret_cast<const float4*>(&hs[b][GRP * 4]);
        acc[b] += wv.x * hv.x + wv.y * hv.y + wv.z * hv.z + wv.w * hv.w;
    }
}
template<int BT, size_t... Is>
__device__ __forceinline__ void gemv_lds(std::index_sequence<Is...>,
                                         const float* __restrict__ wl, int row,
                                         const float (*hs)[HH],
                                         float* __restrict__ acc) {
    (fma_lds_step<(int)Is, BT>(wl, row, hs, acc), ...);
}

template<int K, bool EMB, bool WRITE_SEQ>
__global__ __launch_bounds__(640, 3)
void gru_old(const float* __restrict__ xin,
             const int*   __restrict__ tgt,
             const float* __restrict__ emb,
             const float* __restrict__ Wih,
             const float* __restrict__ Whh,
             const float* __restrict__ bih,
             const float* __restrict__ bhh,
             const float* __restrict__ h_init,
             float* __restrict__ seq_out,
             float* __restrict__ h_last,
             int T)
{
    constexpr int KP = (K + 3) & ~3;
    constexpr int BT = 2;
    constexpr int NT = 2;
    static_assert(KP % 4 == 0, "");

    const int tid  = threadIdx.x;
    const int team = tid / 320;
    const int tj   = tid % 320;
    const int bb0  = blockIdx.x * (BT * NT) + team * BT;
    const int g    = tj / 100;
    const int i    = tj % 100;

    __shared__ __align__(16) float whh_l[(HH / 4) * GG * 4];
    __shared__ __align__(16) float h_s[NT][BT][HH];
    __shared__ __align__(16) float x_s[NT][BT][KP];
    __shared__ float r_s[NT][BT][HH];
    __shared__ float z_s[NT][BT][HH];
    __shared__ float emb_s[EMB ? 64 : 1][EMB ? 28 : 4];
    __shared__ int   tgt_s[NT * BT];

    const int jj = (tj < GG) ? tj : 0;
    float wih[KP];
    ldN(std::make_index_sequence<K>{}, wih, Wih + (long)jj * K);
    #pragma unroll
    for (int k = K; k < KP; ++k) wih[k] = 0.f;
    float bi = bih[jj];
    float bh = bhh[jj];

    for (int idx = tid; idx < GG * HH; idx += 640) {
        int row = idx / HH, k = idx % HH;
        whh_l[((k >> 2) * GG + row) * 4 + (k & 3)] = Whh[row * HH + k];
    }
    for (int idx = tj; idx < BT * HH; idx += 320) {
        int b = idx / HH, k = idx % HH;
        h_s[team][b][k] = h_init ? h_init[(bb0 + b) * HH + k] : 0.f;
    }
    if constexpr (EMB) {
        for (int idx = tid; idx < 64 * 28; idx += 640) {
            int d = idx / 28, k = idx % 28;
            emb_s[d][k] = (k < 26) ? emb[d * 26 + k] : 0.f;
        }
        __syncthreads();
        for (int idx = tj; idx < BT * KP; idx += 320) {
            int b = idx / KP, k = idx % KP;
            int t0 = tgt[bb0 + b];
            x_s[team][b][k] = emb_s[t0][k];
        }
    } else {
        for (int idx = tj; idx < BT * KP; idx += 320) {
            int b = idx / KP, k = idx % KP;
            x_s[team][b][k] = (k < K) ? xin[(bb0 + b) * K + k] : 0.f;
        }
    }
    __syncthreads();

    for (int t = 0; t < T; ++t) {
        pinN(std::make_index_sequence<KP>{}, wih);
        bi = pin_val(bi);
        bh = pin_val(bh);

        const bool has_next = (t + 1 < T);
        float px = 0.f;
        int   ptg = 0;
        if constexpr (!EMB) {
            if (has_next && !(tj >= 200 && tj < 300)) {
                int stid = (tj < 200) ? tj : tj - 100;
                if (stid < BT * K)
                    px = xin[((t + 1) * TB + bb0 + stid / K) * K + stid % K];
            }
        } else {
            if (has_next && tj < BT) ptg = tgt[(t + 1) * TB + bb0 + tj];
        }

        float acc_i[BT], acc_h[BT];
        #pragma unroll
        for (int b = 0; b < BT; ++b) { acc_i[b] = bi; acc_h[b] = bh; }

        gemv4<BT, KP>(std::make_index_sequence<KP / 4>{}, wih, x_s[team], acc_i);
        gemv_lds<BT>(std::make_index_sequence<HH / 4>{}, whh_l, jj, h_s[team], acc_h);

        if (tj < 200) {
            #pragma unroll
            for (int b = 0; b < BT; ++b) {
                float v = sigmoidf_(acc_i[b] + acc_h[b]);
                if (g == 0) r_s[team][b][i] = v;
                else        z_s[team][b][i] = v;
            }
        }
        __syncthreads();

        if (tj >= 200 && tj < 300) {
            #pragma unroll
            for (int b = 0; b < BT; ++b) {
                float n  = tanhf_(acc_i[b] + r_s[team][b][i] * acc_h[b]);
                float z  = z_s[team][b][i];
                float hn = (1.f - z) * n + z * h_s[team][b][i];
                h_s[team][b][i] = hn;
                if (WRITE_SEQ)
                    seq_out[((long)t * TB + bb0 + b) * HH + i] = hn;
            }
        } else if constexpr (!EMB) {
            if (has_next) {
                int stid = (tj < 200) ? tj : tj - 100;
                if (stid < BT * K) x_s[team][stid / K][stid % K] = px;
            }
        }
        if constexpr (EMB) {
            if (has_next && tj < BT) tgt_s[team * BT + tj] = ptg;
            __syncthreads();
            if (has_next && tj < BT * KP) {
                int b = tj / KP, k = tj % KP;
                x_s[team][b][k] = emb_s[tgt_s[team * BT + b]][k];
            }
        }
        __syncthreads();
    }

    if (h_last != nullptr && tj >= 200 && tj < 300) {
        #pragma unroll
        for (int b = 0; b < BT; ++b)
            h_last[(bb0 + b) * HH + i] = h_s[team][b][i];
    }
}

// Final linear + argmax + target_cal.
__global__ __launch_bounds__(256)
void final_kernel(const float* __restrict__ d1,
                  const float* __restrict__ linW,   // [64,100]
                  const float* __restrict__ linb,   // [64]
                  const int*   __restrict__ tgt,    // [80,1024]
                  float* __restrict__ out0,         // [79*1024,64] logits
                  float* __restrict__ out1,         // [79*1024] target_cal
                  float* __restrict__ out2)         // [79*1024] argmax
{
    __shared__ float WT[HH][64];
    __shared__ __align__(16) float row[4][HH];

    const int tid = threadIdx.x;
    for (int idx = tid; idx < 64 * HH; idx += 256) {
        int d = idx / HH, k = idx % HH;
        WT[k][d] = linW[idx];
    }
    const int s    = tid >> 6;
    const int d    = tid & 63;
    const int slot = blockIdx.x * 4 + s;
    const int p    = slot >> 10;
    const int b    = slot & 1023;
    const float* drow = &d1[(long)(p * TB + b) * HH];
    __syncthreads();
    if (d < 50) {
        float2 v = *reinterpret_cast<const float2*>(&drow[2 * d]);
        row[s][2 * d]     = v.x;
        row[s][2 * d + 1] = v.y;
    }
    __syncthreads();

    float acc = linb[d];
    #pragma unroll
    for (int k = 0; k < HH; ++k)
        acc += row[s][k] * WT[k][d];

    out0[(long)slot * 64 + d] = acc;

    float mv = acc;
    int   mi = d;
    #pragma unroll
    for (int off = 32; off >= 1; off >>= 1) {
        float ov = __shfl_xor(mv, off, 64);
        int   oi = __shfl_xor(mi, off, 64);
        if (ov > mv || (ov == mv && oi < mi)) { mv = ov; mi = oi; }
    }
    if (d == 0) out2[slot] = (float)mi;
    if (d == 1) out1[slot] = (float)tgt[(p + 1) * TB + b];
}

extern "C" void kernel_launch(void* const* d_in, const int* in_sizes, int n_in,
                              void* d_out, int out_size, void* d_ws, size_t ws_size,
                              hipStream_t stream)
{
    const float* x      = (const float*)d_in[0];
    const int*   target = (const int*)  d_in[1];
    const float* emb    = (const float*)d_in[2];
    const float* eWih0  = (const float*)d_in[3];
    const float* eWhh0  = (const float*)d_in[4];
    const float* ebih0  = (const float*)d_in[5];
    const float* ebhh0  = (const float*)d_in[6];
    const float* eWih1  = (const float*)d_in[7];
    const float* eWhh1  = (const float*)d_in[8];
    const float* ebih1  = (const float*)d_in[9];
    const float* ebhh1  = (const float*)d_in[10];
    const float* dWih0  = (const float*)d_in[11];
    const float* dWhh0  = (const float*)d_in[12];
    const float* dbih0  = (const float*)d_in[13];
    const float* dbhh0  = (const float*)d_in[14];
    const float* dWih1  = (const float*)d_in[15];
    const float* dWhh1  = (const float*)d_in[16];
    const float* dbih1  = (const float*)d_in[17];
    const float* dbhh1  = (const float*)d_in[18];
    const float* linW   = (const float*)d_in[19];
    const float* linb   = (const float*)d_in[20];

    // workspace layout (floats): see R16 comment (unchanged).
    float* ws     = (float*)d_ws;
    float* h_enc0 = ws;
    float* h_enc1 = ws + 102400;
    float* e0     = ws + 204800;
    float* d0     = e0;
    float* d1_    = e0 + 8192000;
    float* gi_dec = e0 + 16384000;
    float* table  = e0 + 40960000;
    float* gi_enc = ws + 51404800;

    long ws_floats = (long)(ws_size / 4);
    long avail     = ws_floats - 51404800L;
    long Cmax      = (avail > 0) ? avail / 307200L : 0;
    int  C         = (int)((Cmax > 500) ? 500 : Cmax);
    const bool use_gi = (C >= 50);

    dim3 gG(256), gB(320);        // gemm_gi
    dim3 rG(256), rB(256);        // gru_rec

    if (use_gi) {
        for (int c0 = 0; c0 < 500; c0 += C) {
            int Cc = (500 - c0 < C) ? (500 - c0) : C;
            gemm_gi<26><<<gG, gB, 0, stream>>>(
                x + (long)c0 * TB * 26, eWih0, ebih0, gi_enc, Cc * TB);
            gru_rec<false, true><<<rG, rB, 0, stream>>>(
                gi_enc, nullptr, nullptr, eWhh0, ebhh0,
                c0 ? h_enc0 : nullptr, e0, h_enc0, c0, c0 + Cc);
        }
        for (int c0 = 0; c0 < 500; c0 += C) {
            int Cc = (500 - c0 < C) ? (500 - c0) : C;
            gemm_gi<100><<<gG, gB, 0, stream>>>(
                e0 + (long)c0 * TB * 100, eWih1, ebih1, gi_enc, Cc * TB);
            gru_rec<false, false><<<rG, rB, 0, stream>>>(
                gi_enc, nullptr, nullptr, eWhh1, ebhh1,
                c0 ? h_enc1 : nullptr, nullptr, h_enc1, c0, c0 + Cc);
        }
    } else {
        gru_old<26,  false, true ><<<dim3(256), dim3(640), 0, stream>>>(
            x, nullptr, nullptr, eWih0, eWhh0, ebih0, ebhh0, nullptr, e0, h_enc0, 500);
        gru_old<100, false, false><<<dim3(256), dim3(640), 0, stream>>>(
            e0, nullptr, nullptr, eWih1, eWhh1, ebih1, ebhh1, nullptr, nullptr, h_enc1, 500);
    }

    // decoder layer 0 (K=26, EMB): 64-row gi table, no gi buffer
    gemm_gi<26><<<gG, gB, 0, stream>>>(emb, dWih0, dbih0, table, 64);
    gru_rec<true, true><<<rG, rB, 0, stream>>>(
        nullptr, target, table, dWhh0, dbhh0, h_enc0, d0, nullptr, 0, 80);

    // decoder layer 1 (K=100): full gi fits inside dead e0 region
    gemm_gi<100><<<gG, gB, 0, stream>>>(d0, dWih1, dbih1, gi_dec, 80 * TB);
    gru_rec<false, true><<<rG, rB, 0, stream>>>(
        gi_dec, nullptr, nullptr, dWhh1, dbhh1, h_enc1, d1_, nullptr, 0, 80);

    float* out0 = (float*)d_out;
    float* out1 = out0 + (long)79 * 1024 * 64;
    float* out2 = out1 + 79 * 1024;
    final_kernel<<<dim3(20224), dim3(256), 0, stream>>>(d1_, linW, linb, target,
                                                        out0, out1, out2);
}